// Round 2
// baseline (146.008 us; speedup 1.0000x reference)
//
#include <hip/hip_runtime.h>

#define WSZ 2
#define ZNEAR 0.1f
#define ZFAR 100.0f
#define MAXBINS 8192      // LDS ints per WG (32 KB) = max cells per tile & max bins
#define CSTRIDE 16        // counter padding: 16 ints = 64B = one cache line
#define PPW 4096          // points per workgroup in K1
#define NT 256

// Derive tile geometry from runtime h,w (identical in all kernels).
__device__ __forceinline__ void derive_geom(int h, int w, int& H2, int& W2,
                                            int& rpt, int& cpt, int& tpb) {
    H2 = h * WSZ; W2 = w * WSZ;
    rpt = (W2 > 0) ? ((MAXBINS / W2) & ~1) : 2;   // even rows per tile
    if (rpt < 2) rpt = 2;
    if (rpt > H2) rpt = H2;                        // H2 even, stays even
    cpt = rpt * W2;                                // cells per tile
    tpb = (H2 + rpt - 1) / rpt;                    // tiles per batch
}

__global__ void zero_kernel(int* __restrict__ p, int total) {
    int t = blockIdx.x * blockDim.x + threadIdx.x;
    if (t < total) p[t] = 0;
}

// ---------------------------------------------------------------------------
// K1: projection + beta bilinear (out_conf) + spatial binning of valid points.
// ---------------------------------------------------------------------------
__global__ void __launch_bounds__(NT)
project_bin_kernel(const float* __restrict__ pp,    // [b,7,n]
                   const float* __restrict__ conf,  // [b,n]
                   const float* __restrict__ pose,  // [b,4,4]
                   const float* __restrict__ Kmat,  // [b,3,3]
                   const float* __restrict__ beta,  // [b,1,h,w]
                   const int* __restrict__ d_h,
                   const int* __restrict__ d_w,
                   unsigned int* __restrict__ cellbuf,   // [total]
                   int* __restrict__ counters,           // [nb_ub*CSTRIDE]
                   unsigned int* __restrict__ records,   // [nb_ub*cap]
                   float* __restrict__ out_conf,         // [b*n]
                   int total, int n, int cap) {
    __shared__ int hist[MAXBINS];
    const int h = *d_h, w = *d_w;
    int H2, W2, rpt, cpt, tpb;
    derive_geom(h, w, H2, W2, rpt, cpt, tpb);
    const bool geom_ok = (cpt <= MAXBINS);

    for (int i = threadIdx.x; i < MAXBINS; i += NT) hist[i] = 0;
    __syncthreads();

    const int base_g = blockIdx.x * PPW;

    // ---- phase A: compute, sample, classify ----
    for (int k = 0; k < PPW / NT; ++k) {
        int g = base_g + k * NT + threadIdx.x;
        if (g >= total) continue;
        int b_idx = (int)((unsigned)g / (unsigned)n);
        int i = g - b_idx * n;

        const float* P  = pose + b_idx * 16;
        const float* Kb = Kmat + b_idx * 9;
        const float* ppb = pp + (size_t)b_idx * 7 * n + i;
        float px = ppb[0];
        float py = ppb[(size_t)n];
        float pz = ppb[(size_t)2 * n];
        float pw = ppb[(size_t)3 * n];

        float pc0 = P[0] * px + P[1] * py + P[2]  * pz + P[3]  * pw;
        float pc1 = P[4] * px + P[5] * py + P[6]  * pz + P[7]  * pw;
        float pc2 = P[8] * px + P[9] * py + P[10] * pz + P[11] * pw;

        float fxk = Kb[0], cxk = Kb[2], fyk = Kb[4], cyk = Kb[5];
        float z = fabsf(pc2);
        float xc = pc0 * fxk / z + cxk;
        float yc = pc1 * fyk / z + cyk;

        // ---- conf_sampled (identical fp order to the verified round-1 code) ----
        float gx = xc / (float)(w - 1) * 2.0f - 1.0f;
        float gy = -(yc / (float)(h - 1) * 2.0f - 1.0f);
        float ix = (gx + 1.0f) * 0.5f * (float)(w - 1);
        float iy = (gy + 1.0f) * 0.5f * (float)(h - 1);
        float cs = 0.0f;
        if (ix > -1.0f && ix < (float)w && iy > -1.0f && iy < (float)h) {
            float x0f = floorf(ix), y0f = floorf(iy);
            float wx = ix - x0f, wy = iy - y0f;
            int x0 = (int)x0f, y0 = (int)y0f;
            const float* B = beta + (size_t)b_idx * h * w;
            float t00 = 0.0f, t10 = 0.0f, t01 = 0.0f, t11 = 0.0f;
            if (y0 >= 0 && y0 < h) {
                if (x0 >= 0 && x0 < w)         t00 = B[y0 * w + x0];
                if (x0 + 1 >= 0 && x0 + 1 < w) t10 = B[y0 * w + x0 + 1];
            }
            if (y0 + 1 >= 0 && y0 + 1 < h) {
                if (x0 >= 0 && x0 < w)         t01 = B[(y0 + 1) * w + x0];
                if (x0 + 1 >= 0 && x0 + 1 < w) t11 = B[(y0 + 1) * w + x0 + 1];
            }
            cs = t00 * (1.0f - wx) * (1.0f - wy)
               + t10 * wx * (1.0f - wy)
               + t01 * (1.0f - wx) * wy
               + t11 * wx * wy;
        }
        out_conf[g] = cs;

        // ---- validity + bin ----
        float cf = conf[g];
        float rx = rintf(xc * (float)WSZ);  // jnp.round = half-to-even
        float ry = rintf(yc * (float)WSZ);
        bool valid = (rx >= 0.0f) && (rx < (float)W2) &&
                     (ry >= 0.0f) && (ry < (float)H2) &&
                     (z >= ZNEAR) && (z <= ZFAR) && (cf > 0.0f);
        unsigned int word = 0xFFFFFFFFu;
        if (valid && geom_ok) {
            int xs = (int)rx, ys = (int)ry;
            int ty = (int)((unsigned)ys / (unsigned)rpt);
            int bin = b_idx * tpb + ty;
            word = ((unsigned)bin << 13) | (unsigned)((ys - ty * rpt) * W2 + xs);
            atomicAdd(&hist[bin], 1);
        }
        cellbuf[g] = word;
    }
    __syncthreads();

    // ---- flush: one global atomicAdd per (WG, non-empty bin); hist -> cursor ----
    for (int bfl = threadIdx.x; bfl < MAXBINS; bfl += NT) {
        int c = hist[bfl];
        int basee = 0;
        if (c > 0) basee = atomicAdd(&counters[bfl * CSTRIDE], c);
        hist[bfl] = basee;
    }
    __syncthreads();

    // ---- phase B: append records (plain stores) ----
    for (int k = 0; k < PPW / NT; ++k) {
        int g = base_g + k * NT + threadIdx.x;
        if (g >= total) continue;
        unsigned int word = cellbuf[g];
        if (word == 0xFFFFFFFFu) continue;
        int bin = (int)(word >> 13);
        unsigned int cib = word & 8191u;
        int slot = atomicAdd(&hist[bin], 1);   // LDS cursor (absolute slot)
        if (slot < cap) {
            int b_idx = (int)((unsigned)g / (unsigned)n);
            int i = g - b_idx * n;
            records[(size_t)bin * cap + slot] = (cib << 19) | (unsigned)i;
        }
    }
}

// ---------------------------------------------------------------------------
// K2: per-bin LDS z-buffer replay + 2x2 argmax-by-conf pool + vflip + outputs.
// ---------------------------------------------------------------------------
__global__ void __launch_bounds__(NT)
pool_bins_kernel(const float* __restrict__ alpha,   // [b,1,h,w]
                 const float* __restrict__ conf,    // [b,n]
                 const int* __restrict__ counters,
                 const unsigned int* __restrict__ records,
                 const int* __restrict__ d_h,
                 const int* __restrict__ d_w,
                 float* __restrict__ out_match,     // [b,h,w]
                 float* __restrict__ out_midx,      // [b,h,w]
                 int b, int n, int hw, int cap) {
    __shared__ int cells[MAXBINS];
    const int h = *d_h, w = *d_w;
    int H2, W2, rpt, cpt, tpb;
    derive_geom(h, w, H2, W2, rpt, cpt, tpb);
    if (cpt > MAXBINS) return;
    const int n_bins = b * tpb;

    for (int bin = blockIdx.x; bin < n_bins; bin += gridDim.x) {
        for (int i = threadIdx.x; i < MAXBINS; i += NT) cells[i] = -1;
        __syncthreads();

        int cnt = counters[bin * CSTRIDE];
        if (cnt > cap) cnt = cap;
        const unsigned int* rec = records + (size_t)bin * cap;
        for (int r = threadIdx.x; r < cnt; r += NT) {
            unsigned int rr = rec[r];
            atomicMax(&cells[rr >> 19], (int)(rr & 0x7FFFFu));  // winner = max idx
        }
        __syncthreads();

        int b_idx = (int)((unsigned)bin / (unsigned)tpb);
        int ty = bin - b_idx * tpb;
        int row0 = ty * rpt;
        int rmax = H2 - row0; if (rmax > rpt) rmax = rpt;       // even
        const float* A = alpha + (size_t)b_idx * hw;
        const float* C = conf + (size_t)b_idx * n;

        for (int q = 0; q < rmax / 2; ++q) {
            int hr = (row0 >> 1) + q;
            int r_out = h - 1 - hr;                              // vertical flip
            for (int c = threadIdx.x; c < w; c += NT) {
                // alpha gate is uniform across the 2x2 window: = alpha[r_out][c]
                float av = A[r_out * w + c];
                float best = 0.0f;
                int besti = -1;
                if (av > 0.0f) {
                    #pragma unroll
                    for (int a = 0; a < 4; ++a) {
                        int dy = a >> 1, dx = a & 1;
                        int widx = cells[(2 * q + dy) * W2 + 2 * c + dx];
                        if (widx >= 0) {
                            float cv = C[widx];                  // always > 0
                            if (cv > best) { best = cv; besti = widx; }
                        }
                    }
                }
                int o = b_idx * hw + r_out * w + c;
                out_match[o] = (best > 0.0f) ? 1.0f : 0.0f;
                out_midx[o]  = (float)besti;
            }
        }
        __syncthreads();
    }
}

extern "C" void kernel_launch(void* const* d_in, const int* in_sizes, int n_in,
                              void* d_out, int out_size, void* d_ws, size_t ws_size,
                              hipStream_t stream) {
    const float* alpha = (const float*)d_in[0];
    const float* beta  = (const float*)d_in[1];
    const float* pp    = (const float*)d_in[2];
    const float* conf  = (const float*)d_in[3];
    const float* pose  = (const float*)d_in[4];
    const float* Kmat  = (const float*)d_in[5];
    const int*   d_h   = (const int*)d_in[6];
    const int*   d_w   = (const int*)d_in[7];

    const int b  = in_sizes[4] / 16;     // pose [b,4,4]
    const int n  = in_sizes[3] / b;      // conf [b,n]
    const int hw = in_sizes[0] / b;      // alpha [b,1,h,w]
    const int total = b * n;

    float* out_match = (float*)d_out;
    float* out_midx  = out_match + (size_t)b * hw;
    float* out_conf  = out_midx + (size_t)b * hw;

    // Upper bound on n_bins for W2 <= 2048 (w <= 1024): tpb <= 4*hw/4096 + 1.
    const int nb_ub = b * (4 * hw / 4096 + 2);

    // Workspace layout: [counters | cellbuf | records]
    long avail_ints = (long)(ws_size / 4);
    long cap_l = (avail_ints - (long)total - (long)nb_ub * CSTRIDE) / (nb_ub > 0 ? nb_ub : 1);
    int cap = (int)cap_l;
    if (cap > 4096) cap = 4096;
    if (cap < 64) cap = 64;

    int* counters = (int*)d_ws;
    unsigned int* cellbuf = (unsigned int*)(counters + (size_t)nb_ub * CSTRIDE);
    unsigned int* records = cellbuf + (size_t)total;

    const int cnt_total = nb_ub * CSTRIDE;
    zero_kernel<<<(cnt_total + NT - 1) / NT, NT, 0, stream>>>(counters, cnt_total);

    const int g1 = (total + PPW - 1) / PPW;
    project_bin_kernel<<<g1, NT, 0, stream>>>(
        pp, conf, pose, Kmat, beta, d_h, d_w,
        cellbuf, counters, records, out_conf, total, n, cap);

    pool_bins_kernel<<<2048, NT, 0, stream>>>(
        alpha, conf, counters, records, d_h, d_w,
        out_match, out_midx, b, n, hw, cap);
}